// Round 8
// baseline (615.617 us; speedup 1.0000x reference)
//
#include <hip/hip_runtime.h>
#include <hip/hip_bf16.h>
#include <math.h>

#define NPTS 65536
#define KNB  16

typedef __attribute__((ext_vector_type(8))) short bf16x8;
typedef __attribute__((ext_vector_type(4))) float f32x4;

// Fast exact-grade GELU: erf via Abramowitz-Stegun 7.1.26 (|eps|<=1.5e-7).
__device__ __forceinline__ float gelu_f(float v) {
    const float z  = v * 0.70710678118654752f;
    const float az = fabsf(z);
    const float t  = __builtin_amdgcn_rcpf(fmaf(0.3275911f, az, 1.0f));
    float p = fmaf(t, 1.061405429f, -1.453152027f);
    p = fmaf(t, p, 1.421413741f);
    p = fmaf(t, p, -0.284496736f);
    p = fmaf(t, p, 0.254829592f);
    p = p * t;
    const float e  = __expf(-z * z);
    float er = fmaf(-p, e, 1.0f);
    er = copysignf(er, z);
    return 0.5f * v * (1.0f + er);
}

__device__ __forceinline__ short f2bf_s(float v) {
    __hip_bfloat16 h = __float2bfloat16(v);
    return *reinterpret_cast<short*>(&h);
}

// ---------------------------------------------------------------------------
// Weight prep: transpose all GEMM weights to W^T [N][K] bf16. Head BN folded.
// ---------------------------------------------------------------------------
__global__ __launch_bounds__(256) void prep_weights(
    const float* __restrict__ m0_w1, const float* __restrict__ m0_w2,
    const float* __restrict__ ms_w1, const float* __restrict__ ms_w2,
    const float* __restrict__ lfp_w,
    const float* __restrict__ pp_w, const float* __restrict__ pp_g,
    const float* __restrict__ pp_b,
    __hip_bfloat16* __restrict__ w_m0w1t, __hip_bfloat16* __restrict__ w_m0w2t,
    __hip_bfloat16* __restrict__ w_msw1t, __hip_bfloat16* __restrict__ w_msw2t,
    __hip_bfloat16* __restrict__ w_lfpt,  __hip_bfloat16* __restrict__ w_ppt,
    float* __restrict__ c_pp)
{
    int idx = blockIdx.x * 256 + threadIdx.x;
    if (idx < 36864) {                       // m0_w1^T [384][96]
        int n = idx / 96, k = idx % 96;
        w_m0w1t[idx] = __float2bfloat16(m0_w1[k * 384 + n]);
        return;
    }
    idx -= 36864;
    if (idx < 36864) {                       // m0_w2^T [96][384]
        int n = idx / 384, k = idx % 384;
        w_m0w2t[idx] = __float2bfloat16(m0_w2[k * 96 + n]);
        return;
    }
    idx -= 36864;
    if (idx < 2 * 36864) {                   // ms_w1^T[j] [384][96]
        int j = idx / 36864, r = idx % 36864;
        int n = r / 96, k = r % 96;
        w_msw1t[idx] = __float2bfloat16(ms_w1[j * 36864 + k * 384 + n]);
        return;
    }
    idx -= 2 * 36864;
    if (idx < 2 * 36864) {                   // ms_w2^T[j] [96][384]
        int j = idx / 36864, r = idx % 36864;
        int n = r / 384, k = r % 384;
        w_msw2t[idx] = __float2bfloat16(ms_w2[j * 36864 + k * 96 + n]);
        return;
    }
    idx -= 2 * 36864;
    if (idx < 4 * 9216) {                    // lfp_w^T[i] [96][96]
        int i = idx / 9216, r = idx % 9216;
        int n = r / 96, k = r % 96;
        w_lfpt[idx] = __float2bfloat16(lfp_w[i * 9216 + k * 96 + n]);
        return;
    }
    idx -= 4 * 9216;
    if (idx < 24576) {                       // (pp_g * pp_w)^T [256][96]
        int n = idx / 96, k = idx % 96;
        w_ppt[idx] = __float2bfloat16(pp_g[k] * pp_w[k * 256 + n]);
        return;
    }
    idx -= 24576;
    if (idx < 256) {                         // c_pp[n] = sum_k pp_b[k]*pp_w[k][n]
        float s = 0.f;
        for (int k = 0; k < 96; ++k) s += pp_b[k] * pp_w[k * 256 + idx];
        c_pp[idx] = s;
    }
}

// ---------------------------------------------------------------------------
// Neighbor embedding v3: 64 points/block (4 groups of 16), weight fragments
// in registers straight from global (w2 2KB / w3 12KB are L1-resident), only
// h16s/h32s/w1s in LDS (~33.5KB -> 4 blocks/CU).
// ---------------------------------------------------------------------------
__global__ __launch_bounds__(256) void ne_kernel(
    const float* __restrict__ x, const float* __restrict__ xyz,
    const int* __restrict__ knn,
    const float* __restrict__ w1, const float* __restrict__ g1, const float* __restrict__ b1,
    const float* __restrict__ w2, const float* __restrict__ g2, const float* __restrict__ b2,
    const float* __restrict__ w3,
    const float* __restrict__ ng, const float* __restrict__ nb,
    float* __restrict__ f, __hip_bfloat16* __restrict__ fbf)
{
    __shared__ float w1s[112];
    __shared__ float g1s[16], b1s[16];
    __shared__ short h16s[256][24];   // 12.3KB
    __shared__ short h32s[256][40];   // 20.5KB

    const int tid  = threadIdx.x;
    const int wave = tid >> 6;
    const int lane = tid & 63;
    const int lr   = lane & 15;
    const int kc   = (lane >> 4) * 8;

    if (tid < 112) w1s[tid] = w1[tid];
    if (tid < 16) { g1s[tid] = g1[tid]; b1s[tid] = b1[tid]; }

    const f32x4 zero = {0.f, 0.f, 0.f, 0.f};
    const bf16x8 zero8 = {0, 0, 0, 0, 0, 0, 0, 0};

    // --- per-lane weight fragments from global (L1-cached, loaded once) ---
    bf16x8 w2v0 = zero8, w2v1 = zero8;
    if (lane < 32) {
#pragma unroll
        for (int j = 0; j < 8; ++j) {
            w2v0[j] = f2bf_s(w2[(kc + j) * 32 + lr]);
            w2v1[j] = f2bf_s(w2[(kc + j) * 32 + 16 + lr]);
        }
    }
    bf16x8 bv[6];
#pragma unroll
    for (int ct = 0; ct < 6; ++ct)
#pragma unroll
        for (int j = 0; j < 8; ++j)
            bv[ct][j] = f2bf_s(w3[(kc + j) * 96 + ct * 16 + lr]);

    const float g2r0 = g2[lr],      b2r0 = b2[lr];
    const float g2r1 = g2[16 + lr], b2r1 = b2[16 + lr];
    float ngv[6], nbv[6];
    if (lane < 16) {
#pragma unroll
        for (int ct = 0; ct < 6; ++ct) {
            ngv[ct] = ng[ct * 16 + lane];
            nbv[ct] = nb[ct * 16 + lane];
        }
    }

    const int pl = tid >> 4;          // point-in-group 0..15
    const int k  = tid & 15;          // neighbor
    __syncthreads();

#pragma unroll 1
    for (int grp = 0; grp < 4; ++grp) {
        const int p = blockIdx.x * 64 + grp * 16 + pl;
        const int j = knn[p * KNB + k];

        float in7[7];
        {
            float cx0 = xyz[p * 3 + 0], cx1 = xyz[p * 3 + 1], cx2 = xyz[p * 3 + 2];
            in7[0] = xyz[j * 3 + 0] - cx0;
            in7[1] = xyz[j * 3 + 1] - cx1;
            in7[2] = xyz[j * 3 + 2] - cx2;
            in7[3] = x[j * 4 + 0];
            in7[4] = x[j * 4 + 1];
            in7[5] = x[j * 4 + 2];
            in7[6] = x[j * 4 + 3];
        }

        // stage 1 (VALU): 7 -> 16, bn, gelu -> h16s[tid]
        {
            bf16x8 t0, t1;
#pragma unroll
            for (int o = 0; o < 16; ++o) {
                float s = 0.f;
#pragma unroll
                for (int c = 0; c < 7; ++c) s += in7[c] * w1s[c * 16 + o];
                const float hv = gelu_f(s * g1s[o] + b1s[o]);
                if (o < 8) t0[o] = f2bf_s(hv); else t1[o - 8] = f2bf_s(hv);
            }
            *(bf16x8*)&h16s[tid][0] = t0;
            *(bf16x8*)&h16s[tid][8] = t1;
        }
        __syncthreads();

        // stage 2 (MFMA, K zero-padded 16->32): 16 -> 32, bn, gelu -> h32s
#pragma unroll
        for (int pp = 0; pp < 4; ++pp) {
            const int lpl = wave * 4 + pp;
            bf16x8 av = zero8;
            if (lane < 32) av = *(const bf16x8*)&h16s[lpl * 16 + lr][kc];
            f32x4 c0 = __builtin_amdgcn_mfma_f32_16x16x32_bf16(av, w2v0, zero, 0, 0, 0);
            f32x4 c1 = __builtin_amdgcn_mfma_f32_16x16x32_bf16(av, w2v1, zero, 0, 0, 0);
#pragma unroll
            for (int r = 0; r < 4; ++r) {
                const int erow = lpl * 16 + (lane >> 4) * 4 + r;
                h32s[erow][lr]      = f2bf_s(gelu_f(fmaf(c0[r], g2r0, b2r0)));
                h32s[erow][16 + lr] = f2bf_s(gelu_f(fmaf(c1[r], g2r1, b2r1)));
            }
        }
        __syncthreads();

        // stage 3 (MFMA) + neighbor max + BN
#pragma unroll
        for (int pp = 0; pp < 4; ++pp) {
            const int lpl = wave * 4 + pp;
            const int gp  = blockIdx.x * 64 + grp * 16 + lpl;
            const bf16x8 av = *(const bf16x8*)&h32s[lpl * 16 + lr][kc];
#pragma unroll
            for (int ct = 0; ct < 6; ++ct) {
                f32x4 a = __builtin_amdgcn_mfma_f32_16x16x32_bf16(av, bv[ct], zero, 0, 0, 0);
                float m = fmaxf(fmaxf(a[0], a[1]), fmaxf(a[2], a[3]));
                m = fmaxf(m, __shfl_xor(m, 16));
                m = fmaxf(m, __shfl_xor(m, 32));
                if (lane < 16) {
                    const float val = m * ngv[ct] + nbv[ct];
                    f[(size_t)gp * 96 + ct * 16 + lane] = val;
                    fbf[(size_t)gp * 96 + ct * 16 + lane] = __float2bfloat16(val);
                }
            }
        }
        // next grp's stage-1 write to h16s is fenced by the stage-1 barrier
    }
}

// ---------------------------------------------------------------------------
// Fused MLP v2: f += bn(gelu(f@W1+b1)@W2).  Block = 128 rows, 4 waves,
// each wave owns 2 row-tiles (32 rows). Same 4 barriers/c-iter, 2x work.
// ---------------------------------------------------------------------------
__global__ __launch_bounds__(256) void mlp_fused(
    const __hip_bfloat16* __restrict__ w1t, const float* __restrict__ b1,
    const __hip_bfloat16* __restrict__ w2t,
    const float* __restrict__ g, const float* __restrict__ b,
    float* __restrict__ f, __hip_bfloat16* __restrict__ fbf)
{
    __shared__ short As[128 * 104];    // 26.6KB
    __shared__ short Hs[128 * 72];     // 18.4KB
    __shared__ short Bs[96 * 72];      // 13.5KB (also holds 64x104 W1 slice)
    __shared__ float bias_s[384];
    __shared__ float gs[96], bs[96];

    const int tid  = threadIdx.x;
    const int wave = tid >> 6;
    const int lane = tid & 63;
    const int lr   = lane & 15;
    const int kc   = (lane >> 4) * 8;
    const int row0 = blockIdx.x * 128;

    const short* fb = (const short*)fbf;
    const short* w1 = (const short*)w1t;
    const short* w2 = (const short*)w2t;

    // stage A (128x96) + biases
    for (int i = tid; i < 128 * 12; i += 256) {
        const int r = i / 12, c8 = (i % 12) * 8;
        *(bf16x8*)&As[r * 104 + c8] = *(const bf16x8*)&fb[(size_t)(row0 + r) * 96 + c8];
    }
    for (int i = tid; i < 384; i += 256) bias_s[i] = b1[i];
    if (tid < 96) { gs[tid] = g[tid]; bs[tid] = b[tid]; }

    f32x4 acc2[2][6];
#pragma unroll
    for (int rt = 0; rt < 2; ++rt)
#pragma unroll
        for (int i = 0; i < 6; ++i) acc2[rt][i] = f32x4{0.f, 0.f, 0.f, 0.f};

    for (int c = 0; c < 6; ++c) {
        __syncthreads();
        // stage W1^T slice: rows c*64..+64, all 96 k (stride 104)
        for (int i = tid; i < 64 * 12; i += 256) {
            const int r = i / 12, c8 = (i % 12) * 8;
            *(bf16x8*)&Bs[r * 104 + c8] =
                *(const bf16x8*)&w1[(size_t)(c * 64 + r) * 96 + c8];
        }
        __syncthreads();

        // layer 1: h_chunk = gelu(A @ W1_slice^T + b1)
        {
            f32x4 acc1[2][4];
#pragma unroll
            for (int rt = 0; rt < 2; ++rt)
#pragma unroll
                for (int i = 0; i < 4; ++i) acc1[rt][i] = f32x4{0.f, 0.f, 0.f, 0.f};
#pragma unroll
            for (int k0 = 0; k0 < 96; k0 += 32) {
#pragma unroll
                for (int rt = 0; rt < 2; ++rt) {
                    const bf16x8 av =
                        *(const bf16x8*)&As[((wave * 2 + rt) * 16 + lr) * 104 + k0 + kc];
#pragma unroll
                    for (int ct = 0; ct < 4; ++ct) {
                        const bf16x8 bvv =
                            *(const bf16x8*)&Bs[(ct * 16 + lr) * 104 + k0 + kc];
                        acc1[rt][ct] =
                            __builtin_amdgcn_mfma_f32_16x16x32_bf16(av, bvv, acc1[rt][ct], 0, 0, 0);
                    }
                }
            }
#pragma unroll
            for (int rt = 0; rt < 2; ++rt) {
                const int er = (wave * 2 + rt) * 16 + ((lane >> 4) << 2);
#pragma unroll
                for (int ct = 0; ct < 4; ++ct) {
                    const int cl = ct * 16 + lr;
                    const float bb1 = bias_s[c * 64 + cl];
#pragma unroll
                    for (int r = 0; r < 4; ++r)
                        Hs[(er + r) * 72 + cl] = f2bf_s(gelu_f(acc1[rt][ct][r] + bb1));
                }
            }
        }
        __syncthreads();

        // stage W2^T chunk: 96 rows x k-cols c*64..+64 (stride 72)
        for (int i = tid; i < 96 * 8; i += 256) {
            const int r = i >> 3, ko = (i & 7) * 8;
            *(bf16x8*)&Bs[r * 72 + ko] =
                *(const bf16x8*)&w2[(size_t)r * 384 + c * 64 + ko];
        }
        __syncthreads();

        // layer 2 partial: acc2 += h_chunk @ W2_chunk^T
#pragma unroll
        for (int ks = 0; ks < 64; ks += 32) {
#pragma unroll
            for (int rt = 0; rt < 2; ++rt) {
                const bf16x8 av =
                    *(const bf16x8*)&Hs[((wave * 2 + rt) * 16 + lr) * 72 + ks + kc];
#pragma unroll
                for (int ct = 0; ct < 6; ++ct) {
                    const bf16x8 bvv = *(const bf16x8*)&Bs[(ct * 16 + lr) * 72 + ks + kc];
                    acc2[rt][ct] =
                        __builtin_amdgcn_mfma_f32_16x16x32_bf16(av, bvv, acc2[rt][ct], 0, 0, 0);
                }
            }
        }
    }

    // epilogue: f += acc2*g + b
#pragma unroll
    for (int rt = 0; rt < 2; ++rt) {
        const int er = (wave * 2 + rt) * 16 + ((lane >> 4) << 2);
#pragma unroll
        for (int ct = 0; ct < 6; ++ct) {
            const int col = ct * 16 + lr;
            const float gg = gs[col], bb = bs[col];
#pragma unroll
            for (int r = 0; r < 4; ++r) {
                const size_t o = (size_t)(row0 + er + r) * 96 + col;
                const float nf = f[o] + acc2[rt][ct][r] * gg + bb;
                f[o] = nf;
                fbf[o] = __float2bfloat16(nf);
            }
        }
    }
}

// ---------------------------------------------------------------------------
// LFP projection v2: y = f @ lfp_w, 128 rows/block, A+W LDS-resident.
// ---------------------------------------------------------------------------
__global__ __launch_bounds__(256) void proj_kernel(
    const __hip_bfloat16* __restrict__ fbf,
    const __hip_bfloat16* __restrict__ wT,
    float* __restrict__ y)
{
    __shared__ short As[128 * 104];
    __shared__ short Ws[96 * 104];

    const int tid  = threadIdx.x;
    const int wave = tid >> 6;
    const int lane = tid & 63;
    const int lr   = lane & 15;
    const int kc   = (lane >> 4) * 8;
    const int row0 = blockIdx.x * 128;

    const short* fb = (const short*)fbf;
    const short* wg = (const short*)wT;

    for (int i = tid; i < 128 * 12; i += 256) {
        const int r = i / 12, c8 = (i % 12) * 8;
        *(bf16x8*)&As[r * 104 + c8] = *(const bf16x8*)&fb[(size_t)(row0 + r) * 96 + c8];
    }
    for (int i = tid; i < 96 * 12; i += 256) {
        const int r = i / 12, c8 = (i % 12) * 8;
        *(bf16x8*)&Ws[r * 104 + c8] = *(const bf16x8*)&wg[(size_t)r * 96 + c8];
    }
    __syncthreads();

    f32x4 acc[2][6];
#pragma unroll
    for (int rt = 0; rt < 2; ++rt)
#pragma unroll
        for (int i = 0; i < 6; ++i) acc[rt][i] = f32x4{0.f, 0.f, 0.f, 0.f};

#pragma unroll
    for (int k0 = 0; k0 < 96; k0 += 32) {
#pragma unroll
        for (int rt = 0; rt < 2; ++rt) {
            const bf16x8 av =
                *(const bf16x8*)&As[((wave * 2 + rt) * 16 + lr) * 104 + k0 + kc];
#pragma unroll
            for (int ct = 0; ct < 6; ++ct) {
                const bf16x8 bvv = *(const bf16x8*)&Ws[(ct * 16 + lr) * 104 + k0 + kc];
                acc[rt][ct] =
                    __builtin_amdgcn_mfma_f32_16x16x32_bf16(av, bvv, acc[rt][ct], 0, 0, 0);
            }
        }
    }

#pragma unroll
    for (int rt = 0; rt < 2; ++rt) {
        const int er = (wave * 2 + rt) * 16 + ((lane >> 4) << 2);
#pragma unroll
        for (int ct = 0; ct < 6; ++ct) {
            const int col = ct * 16 + lr;
#pragma unroll
            for (int r = 0; r < 4; ++r)
                y[(size_t)(row0 + er + r) * 96 + col] = acc[rt][ct][r];
        }
    }
}

// ---------------------------------------------------------------------------
// Head: out = fbf @ w_ppt^T + c_pp  (A resident; 4 n-tiles of 64).
// ---------------------------------------------------------------------------
__global__ __launch_bounds__(256) void head_kernel(
    const __hip_bfloat16* __restrict__ fbf,
    const __hip_bfloat16* __restrict__ wT,     // [256][96]
    const float* __restrict__ c_pp,
    float* __restrict__ out)
{
    __shared__ short As[64 * 104];
    __shared__ short Bs[64 * 104];
    __shared__ float cpps[256];

    const int tid  = threadIdx.x;
    const int wave = tid >> 6;
    const int lane = tid & 63;
    const int lr   = lane & 15;
    const int kc   = (lane >> 4) * 8;
    const int row0 = blockIdx.x * 64;

    const short* fb = (const short*)fbf;
    const short* wg = (const short*)wT;

    {
        const int sr = tid >> 2, sk = (tid & 3) * 8;
#pragma unroll
        for (int i = 0; i < 3; ++i)
            *(bf16x8*)&As[sr * 104 + sk + 32 * i] =
                *(const bf16x8*)&fb[(size_t)(row0 + sr) * 96 + sk + 32 * i];
        if (tid < 256) cpps[tid] = c_pp[tid];
    }

    for (int nt = 0; nt < 4; ++nt) {
        __syncthreads();
        {
            const int sr = tid >> 2, sk = (tid & 3) * 8;
#pragma unroll
            for (int i = 0; i < 3; ++i)
                *(bf16x8*)&Bs[sr * 104 + sk + 32 * i] =
                    *(const bf16x8*)&wg[(size_t)(nt * 64 + sr) * 96 + sk + 32 * i];
        }
        __syncthreads();

        f32x4 acc[4];
#pragma unroll
        for (int i = 0; i < 4; ++i) acc[i] = f32x4{0.f, 0.f, 0.f, 0.f};
#pragma unroll
        for (int k0 = 0; k0 < 96; k0 += 32) {
            const bf16x8 av = *(const bf16x8*)&As[(wave * 16 + lr) * 104 + k0 + kc];
#pragma unroll
            for (int ct = 0; ct < 4; ++ct) {
                const bf16x8 bvv = *(const bf16x8*)&Bs[(ct * 16 + lr) * 104 + k0 + kc];
                acc[ct] = __builtin_amdgcn_mfma_f32_16x16x32_bf16(av, bvv, acc[ct], 0, 0, 0);
            }
        }

        const int er = wave * 16 + ((lane >> 4) << 2);
#pragma unroll
        for (int ct = 0; ct < 4; ++ct) {
            const int col = nt * 64 + ct * 16 + lr;
#pragma unroll
            for (int r = 0; r < 4; ++r)
                out[(size_t)(row0 + er + r) * 256 + col] = acc[ct][r] + cpps[col];
        }
    }
}

// ---------------------------------------------------------------------------
// LFP gather-max:  f[p] += ( max_k y[knn[p][k]] - y[p] ) * g + b; emits bf16 f.
// ---------------------------------------------------------------------------
__global__ __launch_bounds__(256) void gathermax_kernel(
    const float* __restrict__ y, const int* __restrict__ knn,
    const float* __restrict__ g, const float* __restrict__ b,
    float* __restrict__ f, __hip_bfloat16* __restrict__ fbf)
{
    __shared__ int knns[16][16];
    const int tid = threadIdx.x;
    const int pl  = tid >> 4;
    const int t   = tid & 15;
    const int p0  = blockIdx.x * 16;
    knns[pl][t] = knn[(p0 + pl) * KNB + t];
    __syncthreads();

    const int p   = p0 + pl;
    const int off = t * 6;

    float m[6];
#pragma unroll
    for (int i = 0; i < 6; ++i) m[i] = -INFINITY;

#pragma unroll 4
    for (int k = 0; k < 16; ++k) {
        const int j = knns[pl][k];
        const float* yr = y + (size_t)j * 96 + off;
        const float2 v0 = *(const float2*)(yr + 0);
        const float2 v1 = *(const float2*)(yr + 2);
        const float2 v2 = *(const float2*)(yr + 4);
        m[0] = fmaxf(m[0], v0.x); m[1] = fmaxf(m[1], v0.y);
        m[2] = fmaxf(m[2], v1.x); m[3] = fmaxf(m[3], v1.y);
        m[4] = fmaxf(m[4], v2.x); m[5] = fmaxf(m[5], v2.y);
    }

    const float* yc = y + (size_t)p * 96 + off;
    float* fr = f + (size_t)p * 96 + off;
    __hip_bfloat16* fbr = fbf + (size_t)p * 96 + off;
#pragma unroll
    for (int i = 0; i < 6; ++i) {
        const float nf = fr[i] + (m[i] - yc[i]) * g[off + i] + b[off + i];
        fr[i] = nf;
        fbr[i] = __float2bfloat16(nf);
    }
}

// ---------------------------------------------------------------------------
extern "C" void kernel_launch(void* const* d_in, const int* in_sizes, int n_in,
                              void* d_out, int out_size, void* d_ws, size_t ws_size,
                              hipStream_t stream)
{
    const float* x     = (const float*)d_in[0];
    const float* xyz   = (const float*)d_in[1];
    const int*   knn   = (const int*)d_in[2];
    const float* ne_w1 = (const float*)d_in[3];
    const float* ne_g1 = (const float*)d_in[4];
    const float* ne_b1 = (const float*)d_in[5];
    const float* ne_w2 = (const float*)d_in[6];
    const float* ne_g2 = (const float*)d_in[7];
    const float* ne_b2 = (const float*)d_in[8];
    const float* ne_w3 = (const float*)d_in[9];
    const float* nbr_g = (const float*)d_in[10];
    const float* nbr_b = (const float*)d_in[11];
    const float* m0_w1 = (const float*)d_in[12];
    const float* m0_b1 = (const float*)d_in[13];
    const float* m0_w2 = (const float*)d_in[14];
    const float* m0_g  = (const float*)d_in[15];
    const float* m0_b  = (const float*)d_in[16];
    const float* lfp_w = (const float*)d_in[17];
    const float* lfp_g = (const float*)d_in[18];
    const float* lfp_b = (const float*)d_in[19];
    const float* ms_w1 = (const float*)d_in[20];
    const float* ms_b1 = (const float*)d_in[21];
    const float* ms_w2 = (const float*)d_in[22];
    const float* ms_g  = (const float*)d_in[23];
    const float* ms_b  = (const float*)d_in[24];
    const float* pp_g  = (const float*)d_in[25];
    const float* pp_b  = (const float*)d_in[26];
    const float* pp_w  = (const float*)d_in[27];

    float* out = (float*)d_out;

    // --- workspace layout (all 16B-aligned) ---
    float* f   = (float*)d_ws;                            // [N][96] f32
    float* y   = f + (size_t)NPTS * 96;                   // [N][96] f32
    __hip_bfloat16* fbf = (__hip_bfloat16*)(y + (size_t)NPTS * 96);  // [N][96] bf16
    __hip_bfloat16* w_m0w1t = fbf + (size_t)NPTS * 96;    // [384][96]
    __hip_bfloat16* w_m0w2t = w_m0w1t + 36864;            // [96][384]
    __hip_bfloat16* w_msw1t = w_m0w2t + 36864;            // 2x[384][96]
    __hip_bfloat16* w_msw2t = w_msw1t + 2 * 36864;        // 2x[96][384]
    __hip_bfloat16* w_lfpt  = w_msw2t + 2 * 36864;        // 4x[96][96]
    __hip_bfloat16* w_ppt   = w_lfpt + 4 * 9216;          // [256][96]
    float* c_pp = (float*)(w_ppt + 24576);                // [256] f32

    prep_weights<<<1105, 256, 0, stream>>>(
        m0_w1, m0_w2, ms_w1, ms_w2, lfp_w, pp_w, pp_g, pp_b,
        w_m0w1t, w_m0w2t, w_msw1t, w_msw2t, w_lfpt, w_ppt, c_pp);

    ne_kernel<<<NPTS / 64, 256, 0, stream>>>(x, xyz, knn,
        ne_w1, ne_g1, ne_b1, ne_w2, ne_g2, ne_b2, ne_w3, nbr_g, nbr_b, f, fbf);

    mlp_fused<<<NPTS / 128, 256, 0, stream>>>(
        w_m0w1t, m0_b1, w_m0w2t, m0_g, m0_b, f, fbf);

    for (int i = 0; i < 4; ++i) {
        proj_kernel<<<NPTS / 128, 256, 0, stream>>>(
            fbf, w_lfpt + (size_t)i * 9216, y);
        gathermax_kernel<<<NPTS / 16, 256, 0, stream>>>(
            y, knn, lfp_g + i * 96, lfp_b + i * 96, f, fbf);
        if (i & 1) {
            const int jj = i / 2;
            mlp_fused<<<NPTS / 128, 256, 0, stream>>>(
                w_msw1t + (size_t)jj * 36864, ms_b1 + (size_t)jj * 384,
                w_msw2t + (size_t)jj * 36864, ms_g + jj * 96, ms_b + jj * 96, f, fbf);
        }
    }

    head_kernel<<<NPTS / 64, 256, 0, stream>>>(fbf, w_ppt, c_pp, out);
}

// Round 9
// 493.040 us; speedup vs baseline: 1.2486x; 1.2486x over previous
//
#include <hip/hip_runtime.h>
#include <hip/hip_bf16.h>
#include <hip/hip_fp16.h>
#include <math.h>

#define NPTS 65536
#define KNB  16

typedef __attribute__((ext_vector_type(8))) short bf16x8;
typedef __attribute__((ext_vector_type(4))) float f32x4;

// Fast exact-grade GELU: erf via Abramowitz-Stegun 7.1.26 (|eps|<=1.5e-7).
__device__ __forceinline__ float gelu_f(float v) {
    const float z  = v * 0.70710678118654752f;
    const float az = fabsf(z);
    const float t  = __builtin_amdgcn_rcpf(fmaf(0.3275911f, az, 1.0f));
    float p = fmaf(t, 1.061405429f, -1.453152027f);
    p = fmaf(t, p, 1.421413741f);
    p = fmaf(t, p, -0.284496736f);
    p = fmaf(t, p, 0.254829592f);
    p = p * t;
    const float e  = __expf(-z * z);
    float er = fmaf(-p, e, 1.0f);
    er = copysignf(er, z);
    return 0.5f * v * (1.0f + er);
}

__device__ __forceinline__ short f2bf_s(float v) {
    __hip_bfloat16 h = __float2bfloat16(v);
    return *reinterpret_cast<short*>(&h);
}

// ---------------------------------------------------------------------------
// Weight prep: transpose all GEMM weights to W^T [N][K] bf16. Head BN folded.
// ---------------------------------------------------------------------------
__global__ __launch_bounds__(256) void prep_weights(
    const float* __restrict__ m0_w1, const float* __restrict__ m0_w2,
    const float* __restrict__ ms_w1, const float* __restrict__ ms_w2,
    const float* __restrict__ lfp_w,
    const float* __restrict__ pp_w, const float* __restrict__ pp_g,
    const float* __restrict__ pp_b,
    __hip_bfloat16* __restrict__ w_m0w1t, __hip_bfloat16* __restrict__ w_m0w2t,
    __hip_bfloat16* __restrict__ w_msw1t, __hip_bfloat16* __restrict__ w_msw2t,
    __hip_bfloat16* __restrict__ w_lfpt,  __hip_bfloat16* __restrict__ w_ppt,
    float* __restrict__ c_pp)
{
    int idx = blockIdx.x * 256 + threadIdx.x;
    if (idx < 36864) {                       // m0_w1^T [384][96]
        int n = idx / 96, k = idx % 96;
        w_m0w1t[idx] = __float2bfloat16(m0_w1[k * 384 + n]);
        return;
    }
    idx -= 36864;
    if (idx < 36864) {                       // m0_w2^T [96][384]
        int n = idx / 384, k = idx % 384;
        w_m0w2t[idx] = __float2bfloat16(m0_w2[k * 96 + n]);
        return;
    }
    idx -= 36864;
    if (idx < 2 * 36864) {                   // ms_w1^T[j] [384][96]
        int j = idx / 36864, r = idx % 36864;
        int n = r / 96, k = r % 96;
        w_msw1t[idx] = __float2bfloat16(ms_w1[j * 36864 + k * 384 + n]);
        return;
    }
    idx -= 2 * 36864;
    if (idx < 2 * 36864) {                   // ms_w2^T[j] [96][384]
        int j = idx / 36864, r = idx % 36864;
        int n = r / 384, k = r % 384;
        w_msw2t[idx] = __float2bfloat16(ms_w2[j * 36864 + k * 96 + n]);
        return;
    }
    idx -= 2 * 36864;
    if (idx < 4 * 9216) {                    // lfp_w^T[i] [96][96]
        int i = idx / 9216, r = idx % 9216;
        int n = r / 96, k = r % 96;
        w_lfpt[idx] = __float2bfloat16(lfp_w[i * 9216 + k * 96 + n]);
        return;
    }
    idx -= 4 * 9216;
    if (idx < 24576) {                       // (pp_g * pp_w)^T [256][96]
        int n = idx / 96, k = idx % 96;
        w_ppt[idx] = __float2bfloat16(pp_g[k] * pp_w[k * 256 + n]);
        return;
    }
    idx -= 24576;
    if (idx < 256) {                         // c_pp[n] = sum_k pp_b[k]*pp_w[k][n]
        float s = 0.f;
        for (int k = 0; k < 96; ++k) s += pp_b[k] * pp_w[k * 256 + idx];
        c_pp[idx] = s;
    }
}

// ---------------------------------------------------------------------------
// Neighbor embedding v3: 64 points/block (4 groups of 16), weight fragments
// in registers from global (L1-resident), only h16s/h32s/w1s in LDS.
// ---------------------------------------------------------------------------
__global__ __launch_bounds__(256) void ne_kernel(
    const float* __restrict__ x, const float* __restrict__ xyz,
    const int* __restrict__ knn,
    const float* __restrict__ w1, const float* __restrict__ g1, const float* __restrict__ b1,
    const float* __restrict__ w2, const float* __restrict__ g2, const float* __restrict__ b2,
    const float* __restrict__ w3,
    const float* __restrict__ ng, const float* __restrict__ nb,
    float* __restrict__ f, __hip_bfloat16* __restrict__ fbf)
{
    __shared__ float w1s[112];
    __shared__ float g1s[16], b1s[16];
    __shared__ short h16s[256][24];
    __shared__ short h32s[256][40];

    const int tid  = threadIdx.x;
    const int wave = tid >> 6;
    const int lane = tid & 63;
    const int lr   = lane & 15;
    const int kc   = (lane >> 4) * 8;

    if (tid < 112) w1s[tid] = w1[tid];
    if (tid < 16) { g1s[tid] = g1[tid]; b1s[tid] = b1[tid]; }

    const f32x4 zero = {0.f, 0.f, 0.f, 0.f};
    const bf16x8 zero8 = {0, 0, 0, 0, 0, 0, 0, 0};

    bf16x8 w2v0 = zero8, w2v1 = zero8;
    if (lane < 32) {
#pragma unroll
        for (int j = 0; j < 8; ++j) {
            w2v0[j] = f2bf_s(w2[(kc + j) * 32 + lr]);
            w2v1[j] = f2bf_s(w2[(kc + j) * 32 + 16 + lr]);
        }
    }
    bf16x8 bv[6];
#pragma unroll
    for (int ct = 0; ct < 6; ++ct)
#pragma unroll
        for (int j = 0; j < 8; ++j)
            bv[ct][j] = f2bf_s(w3[(kc + j) * 96 + ct * 16 + lr]);

    const float g2r0 = g2[lr],      b2r0 = b2[lr];
    const float g2r1 = g2[16 + lr], b2r1 = b2[16 + lr];
    float ngv[6], nbv[6];
    if (lane < 16) {
#pragma unroll
        for (int ct = 0; ct < 6; ++ct) {
            ngv[ct] = ng[ct * 16 + lane];
            nbv[ct] = nb[ct * 16 + lane];
        }
    }

    const int pl = tid >> 4;
    const int k  = tid & 15;
    __syncthreads();

#pragma unroll 1
    for (int grp = 0; grp < 4; ++grp) {
        const int p = blockIdx.x * 64 + grp * 16 + pl;
        const int j = knn[p * KNB + k];

        float in7[7];
        {
            float cx0 = xyz[p * 3 + 0], cx1 = xyz[p * 3 + 1], cx2 = xyz[p * 3 + 2];
            in7[0] = xyz[j * 3 + 0] - cx0;
            in7[1] = xyz[j * 3 + 1] - cx1;
            in7[2] = xyz[j * 3 + 2] - cx2;
            in7[3] = x[j * 4 + 0];
            in7[4] = x[j * 4 + 1];
            in7[5] = x[j * 4 + 2];
            in7[6] = x[j * 4 + 3];
        }

        {
            bf16x8 t0, t1;
#pragma unroll
            for (int o = 0; o < 16; ++o) {
                float s = 0.f;
#pragma unroll
                for (int c = 0; c < 7; ++c) s += in7[c] * w1s[c * 16 + o];
                const float hv = gelu_f(s * g1s[o] + b1s[o]);
                if (o < 8) t0[o] = f2bf_s(hv); else t1[o - 8] = f2bf_s(hv);
            }
            *(bf16x8*)&h16s[tid][0] = t0;
            *(bf16x8*)&h16s[tid][8] = t1;
        }
        __syncthreads();

#pragma unroll
        for (int pp = 0; pp < 4; ++pp) {
            const int lpl = wave * 4 + pp;
            bf16x8 av = zero8;
            if (lane < 32) av = *(const bf16x8*)&h16s[lpl * 16 + lr][kc];
            f32x4 c0 = __builtin_amdgcn_mfma_f32_16x16x32_bf16(av, w2v0, zero, 0, 0, 0);
            f32x4 c1 = __builtin_amdgcn_mfma_f32_16x16x32_bf16(av, w2v1, zero, 0, 0, 0);
#pragma unroll
            for (int r = 0; r < 4; ++r) {
                const int erow = lpl * 16 + (lane >> 4) * 4 + r;
                h32s[erow][lr]      = f2bf_s(gelu_f(fmaf(c0[r], g2r0, b2r0)));
                h32s[erow][16 + lr] = f2bf_s(gelu_f(fmaf(c1[r], g2r1, b2r1)));
            }
        }
        __syncthreads();

#pragma unroll
        for (int pp = 0; pp < 4; ++pp) {
            const int lpl = wave * 4 + pp;
            const int gp  = blockIdx.x * 64 + grp * 16 + lpl;
            const bf16x8 av = *(const bf16x8*)&h32s[lpl * 16 + lr][kc];
#pragma unroll
            for (int ct = 0; ct < 6; ++ct) {
                f32x4 a = __builtin_amdgcn_mfma_f32_16x16x32_bf16(av, bv[ct], zero, 0, 0, 0);
                float m = fmaxf(fmaxf(a[0], a[1]), fmaxf(a[2], a[3]));
                m = fmaxf(m, __shfl_xor(m, 16));
                m = fmaxf(m, __shfl_xor(m, 32));
                if (lane < 16) {
                    const float val = m * ngv[ct] + nbv[ct];
                    f[(size_t)gp * 96 + ct * 16 + lane] = val;
                    fbf[(size_t)gp * 96 + ct * 16 + lane] = __float2bfloat16(val);
                }
            }
        }
    }
}

// ---------------------------------------------------------------------------
// Fused MLP (round-7 64-row config): f += bn(gelu(f@W1+b1)@W2).
// ---------------------------------------------------------------------------
__global__ __launch_bounds__(256) void mlp_fused(
    const __hip_bfloat16* __restrict__ w1t, const float* __restrict__ b1,
    const __hip_bfloat16* __restrict__ w2t,
    const float* __restrict__ g, const float* __restrict__ b,
    float* __restrict__ f, __hip_bfloat16* __restrict__ fbf)
{
    __shared__ short As[64 * 104];
    __shared__ short Hs[64 * 72];
    __shared__ short Bs[6912];
    __shared__ float bias_s[384];
    __shared__ float gs[96], bs[96];

    const int tid  = threadIdx.x;
    const int wave = tid >> 6;
    const int lane = tid & 63;
    const int lr   = lane & 15;
    const int kc   = (lane >> 4) * 8;
    const int row0 = blockIdx.x * 64;

    const short* fb = (const short*)fbf;
    const short* w1 = (const short*)w1t;
    const short* w2 = (const short*)w2t;

    {
        const int sr = tid >> 2, sk = (tid & 3) * 8;
#pragma unroll
        for (int i = 0; i < 3; ++i)
            *(bf16x8*)&As[sr * 104 + sk + 32 * i] =
                *(const bf16x8*)&fb[(size_t)(row0 + sr) * 96 + sk + 32 * i];
        for (int i = tid; i < 384; i += 256) bias_s[i] = b1[i];
        if (tid < 96) { gs[tid] = g[tid]; bs[tid] = b[tid]; }
    }

    f32x4 acc2[6];
#pragma unroll
    for (int i = 0; i < 6; ++i) acc2[i] = f32x4{0.f, 0.f, 0.f, 0.f};

    for (int c = 0; c < 6; ++c) {
        __syncthreads();
        {
            const int sr = tid >> 2, sk = (tid & 3) * 8;
#pragma unroll
            for (int i = 0; i < 3; ++i)
                *(bf16x8*)&Bs[sr * 104 + sk + 32 * i] =
                    *(const bf16x8*)&w1[(size_t)(c * 64 + sr) * 96 + sk + 32 * i];
        }
        __syncthreads();

        {
            f32x4 acc1[4];
#pragma unroll
            for (int i = 0; i < 4; ++i) acc1[i] = f32x4{0.f, 0.f, 0.f, 0.f};
#pragma unroll
            for (int k0 = 0; k0 < 96; k0 += 32) {
                const bf16x8 av = *(const bf16x8*)&As[(wave * 16 + lr) * 104 + k0 + kc];
#pragma unroll
                for (int ct = 0; ct < 4; ++ct) {
                    const bf16x8 bvv = *(const bf16x8*)&Bs[(ct * 16 + lr) * 104 + k0 + kc];
                    acc1[ct] = __builtin_amdgcn_mfma_f32_16x16x32_bf16(av, bvv, acc1[ct], 0, 0, 0);
                }
            }
            const int er = wave * 16 + ((lane >> 4) << 2);
#pragma unroll
            for (int ct = 0; ct < 4; ++ct) {
                const int cl = ct * 16 + lr;
                const float bb1 = bias_s[c * 64 + cl];
#pragma unroll
                for (int r = 0; r < 4; ++r)
                    Hs[(er + r) * 72 + cl] = f2bf_s(gelu_f(acc1[ct][r] + bb1));
            }
        }
        __syncthreads();

        {
            for (int i = tid; i < 768; i += 256) {
                const int r = i >> 3, ko = (i & 7) * 8;
                *(bf16x8*)&Bs[r * 72 + ko] =
                    *(const bf16x8*)&w2[(size_t)r * 384 + c * 64 + ko];
            }
        }
        __syncthreads();

#pragma unroll
        for (int ks = 0; ks < 64; ks += 32) {
            const bf16x8 av = *(const bf16x8*)&Hs[(wave * 16 + lr) * 72 + ks + kc];
#pragma unroll
            for (int ct = 0; ct < 6; ++ct) {
                const bf16x8 bvv = *(const bf16x8*)&Bs[(ct * 16 + lr) * 72 + ks + kc];
                acc2[ct] = __builtin_amdgcn_mfma_f32_16x16x32_bf16(av, bvv, acc2[ct], 0, 0, 0);
            }
        }
    }

    const int er = wave * 16 + ((lane >> 4) << 2);
#pragma unroll
    for (int ct = 0; ct < 6; ++ct) {
        const int col = ct * 16 + lr;
        const float gg = gs[col], bb = bs[col];
#pragma unroll
        for (int r = 0; r < 4; ++r) {
            const size_t o = (size_t)(row0 + er + r) * 96 + col;
            const float nf = f[o] + acc2[ct][r] * gg + bb;
            f[o] = nf;
            fbf[o] = __float2bfloat16(nf);
        }
    }
}

// ---------------------------------------------------------------------------
// LFP projection (round-7 64-row config): y = f @ lfp_w, output fp16.
// ---------------------------------------------------------------------------
__global__ __launch_bounds__(256) void proj_kernel(
    const __hip_bfloat16* __restrict__ fbf,
    const __hip_bfloat16* __restrict__ wT,
    __half* __restrict__ y)
{
    __shared__ short As[64 * 104];
    __shared__ short Ws[96 * 104];

    const int tid  = threadIdx.x;
    const int wave = tid >> 6;
    const int lane = tid & 63;
    const int lr   = lane & 15;
    const int kc   = (lane >> 4) * 8;
    const int row0 = blockIdx.x * 64;

    const short* fb = (const short*)fbf;
    const short* wg = (const short*)wT;

    {
        const int sr = tid >> 2, sk = (tid & 3) * 8;
#pragma unroll
        for (int i = 0; i < 3; ++i)
            *(bf16x8*)&As[sr * 104 + sk + 32 * i] =
                *(const bf16x8*)&fb[(size_t)(row0 + sr) * 96 + sk + 32 * i];
        for (int i = tid; i < 1152; i += 256) {
            const int r = i / 12, ko = (i % 12) * 8;
            *(bf16x8*)&Ws[r * 104 + ko] = *(const bf16x8*)&wg[(size_t)r * 96 + ko];
        }
    }
    __syncthreads();

    f32x4 acc[6];
#pragma unroll
    for (int i = 0; i < 6; ++i) acc[i] = f32x4{0.f, 0.f, 0.f, 0.f};

#pragma unroll
    for (int k0 = 0; k0 < 96; k0 += 32) {
        const bf16x8 av = *(const bf16x8*)&As[(wave * 16 + lr) * 104 + k0 + kc];
#pragma unroll
        for (int ct = 0; ct < 6; ++ct) {
            const bf16x8 bvv = *(const bf16x8*)&Ws[(ct * 16 + lr) * 104 + k0 + kc];
            acc[ct] = __builtin_amdgcn_mfma_f32_16x16x32_bf16(av, bvv, acc[ct], 0, 0, 0);
        }
    }

    const int er = wave * 16 + ((lane >> 4) << 2);
#pragma unroll
    for (int ct = 0; ct < 6; ++ct) {
        const int col = ct * 16 + lr;
#pragma unroll
        for (int r = 0; r < 4; ++r)
            y[(size_t)(row0 + er + r) * 96 + col] = __float2half(acc[ct][r]);
    }
}

// ---------------------------------------------------------------------------
// Head: out = fbf @ w_ppt^T + c_pp  (A resident; 4 n-tiles of 64).
// ---------------------------------------------------------------------------
__global__ __launch_bounds__(256) void head_kernel(
    const __hip_bfloat16* __restrict__ fbf,
    const __hip_bfloat16* __restrict__ wT,     // [256][96]
    const float* __restrict__ c_pp,
    float* __restrict__ out)
{
    __shared__ short As[64 * 104];
    __shared__ short Bs[64 * 104];
    __shared__ float cpps[256];

    const int tid  = threadIdx.x;
    const int wave = tid >> 6;
    const int lane = tid & 63;
    const int lr   = lane & 15;
    const int kc   = (lane >> 4) * 8;
    const int row0 = blockIdx.x * 64;

    const short* fb = (const short*)fbf;
    const short* wg = (const short*)wT;

    {
        const int sr = tid >> 2, sk = (tid & 3) * 8;
#pragma unroll
        for (int i = 0; i < 3; ++i)
            *(bf16x8*)&As[sr * 104 + sk + 32 * i] =
                *(const bf16x8*)&fb[(size_t)(row0 + sr) * 96 + sk + 32 * i];
        if (tid < 256) cpps[tid] = c_pp[tid];
    }

    for (int nt = 0; nt < 4; ++nt) {
        __syncthreads();
        {
            const int sr = tid >> 2, sk = (tid & 3) * 8;
#pragma unroll
            for (int i = 0; i < 3; ++i)
                *(bf16x8*)&Bs[sr * 104 + sk + 32 * i] =
                    *(const bf16x8*)&wg[(size_t)(nt * 64 + sr) * 96 + sk + 32 * i];
        }
        __syncthreads();

        f32x4 acc[4];
#pragma unroll
        for (int i = 0; i < 4; ++i) acc[i] = f32x4{0.f, 0.f, 0.f, 0.f};
#pragma unroll
        for (int k0 = 0; k0 < 96; k0 += 32) {
            const bf16x8 av = *(const bf16x8*)&As[(wave * 16 + lr) * 104 + k0 + kc];
#pragma unroll
            for (int ct = 0; ct < 4; ++ct) {
                const bf16x8 bvv = *(const bf16x8*)&Bs[(ct * 16 + lr) * 104 + k0 + kc];
                acc[ct] = __builtin_amdgcn_mfma_f32_16x16x32_bf16(av, bvv, acc[ct], 0, 0, 0);
            }
        }

        const int er = wave * 16 + ((lane >> 4) << 2);
#pragma unroll
        for (int ct = 0; ct < 4; ++ct) {
            const int col = nt * 64 + ct * 16 + lr;
#pragma unroll
            for (int r = 0; r < 4; ++r)
                out[(size_t)(row0 + er + r) * 256 + col] = acc[ct][r] + cpps[col];
        }
    }
}

// ---------------------------------------------------------------------------
// LFP gather-max (fp16 y): f[p] += ( max_k y[knn[p][k]] - y[p] ) * g + b.
// 16 threads/point, 6 fp16 dims per thread (3x 4B half2 loads per row).
// ---------------------------------------------------------------------------
__global__ __launch_bounds__(256) void gathermax_kernel(
    const __half* __restrict__ y, const int* __restrict__ knn,
    const float* __restrict__ g, const float* __restrict__ b,
    float* __restrict__ f, __hip_bfloat16* __restrict__ fbf)
{
    __shared__ int knns[16][16];
    const int tid = threadIdx.x;
    const int pl  = tid >> 4;
    const int t   = tid & 15;
    const int p0  = blockIdx.x * 16;
    knns[pl][t] = knn[(p0 + pl) * KNB + t];
    __syncthreads();

    const int p   = p0 + pl;
    const int off = t * 6;

    float m[6];
#pragma unroll
    for (int i = 0; i < 6; ++i) m[i] = -INFINITY;

#pragma unroll 4
    for (int k = 0; k < 16; ++k) {
        const int j = knns[pl][k];
        const __half* yr = y + (size_t)j * 96 + off;
        const float2 v0 = __half22float2(*(const __half2*)(yr + 0));
        const float2 v1 = __half22float2(*(const __half2*)(yr + 2));
        const float2 v2 = __half22float2(*(const __half2*)(yr + 4));
        m[0] = fmaxf(m[0], v0.x); m[1] = fmaxf(m[1], v0.y);
        m[2] = fmaxf(m[2], v1.x); m[3] = fmaxf(m[3], v1.y);
        m[4] = fmaxf(m[4], v2.x); m[5] = fmaxf(m[5], v2.y);
    }

    const __half* yc = y + (size_t)p * 96 + off;
    const float2 c0 = __half22float2(*(const __half2*)(yc + 0));
    const float2 c1 = __half22float2(*(const __half2*)(yc + 2));
    const float2 c2 = __half22float2(*(const __half2*)(yc + 4));
    const float cself[6] = {c0.x, c0.y, c1.x, c1.y, c2.x, c2.y};

    float* fr = f + (size_t)p * 96 + off;
    __hip_bfloat16* fbr = fbf + (size_t)p * 96 + off;
#pragma unroll
    for (int i = 0; i < 6; ++i) {
        const float nf = fr[i] + (m[i] - cself[i]) * g[off + i] + b[off + i];
        fr[i] = nf;
        fbr[i] = __float2bfloat16(nf);
    }
}

// ---------------------------------------------------------------------------
extern "C" void kernel_launch(void* const* d_in, const int* in_sizes, int n_in,
                              void* d_out, int out_size, void* d_ws, size_t ws_size,
                              hipStream_t stream)
{
    const float* x     = (const float*)d_in[0];
    const float* xyz   = (const float*)d_in[1];
    const int*   knn   = (const int*)d_in[2];
    const float* ne_w1 = (const float*)d_in[3];
    const float* ne_g1 = (const float*)d_in[4];
    const float* ne_b1 = (const float*)d_in[5];
    const float* ne_w2 = (const float*)d_in[6];
    const float* ne_g2 = (const float*)d_in[7];
    const float* ne_b2 = (const float*)d_in[8];
    const float* ne_w3 = (const float*)d_in[9];
    const float* nbr_g = (const float*)d_in[10];
    const float* nbr_b = (const float*)d_in[11];
    const float* m0_w1 = (const float*)d_in[12];
    const float* m0_b1 = (const float*)d_in[13];
    const float* m0_w2 = (const float*)d_in[14];
    const float* m0_g  = (const float*)d_in[15];
    const float* m0_b  = (const float*)d_in[16];
    const float* lfp_w = (const float*)d_in[17];
    const float* lfp_g = (const float*)d_in[18];
    const float* lfp_b = (const float*)d_in[19];
    const float* ms_w1 = (const float*)d_in[20];
    const float* ms_b1 = (const float*)d_in[21];
    const float* ms_w2 = (const float*)d_in[22];
    const float* ms_g  = (const float*)d_in[23];
    const float* ms_b  = (const float*)d_in[24];
    const float* pp_g  = (const float*)d_in[25];
    const float* pp_b  = (const float*)d_in[26];
    const float* pp_w  = (const float*)d_in[27];

    float* out = (float*)d_out;

    // --- workspace layout (y region sized for f32, used as fp16) ---
    float* f   = (float*)d_ws;                            // [N][96] f32
    __half* y  = (__half*)(f + (size_t)NPTS * 96);        // [N][96] fp16
    __hip_bfloat16* fbf = (__hip_bfloat16*)((float*)y + (size_t)NPTS * 96);
    __hip_bfloat16* w_m0w1t = fbf + (size_t)NPTS * 96;    // [384][96]
    __hip_bfloat16* w_m0w2t = w_m0w1t + 36864;            // [96][384]
    __hip_bfloat16* w_msw1t = w_m0w2t + 36864;            // 2x[384][96]
    __hip_bfloat16* w_msw2t = w_msw1t + 2 * 36864;        // 2x[96][384]
    __hip_bfloat16* w_lfpt  = w_msw2t + 2 * 36864;        // 4x[96][96]
    __hip_bfloat16* w_ppt   = w_lfpt + 4 * 9216;          // [256][96]
    float* c_pp = (float*)(w_ppt + 24576);                // [256] f32

    prep_weights<<<1105, 256, 0, stream>>>(
        m0_w1, m0_w2, ms_w1, ms_w2, lfp_w, pp_w, pp_g, pp_b,
        w_m0w1t, w_m0w2t, w_msw1t, w_msw2t, w_lfpt, w_ppt, c_pp);

    ne_kernel<<<NPTS / 64, 256, 0, stream>>>(x, xyz, knn,
        ne_w1, ne_g1, ne_b1, ne_w2, ne_g2, ne_b2, ne_w3, nbr_g, nbr_b, f, fbf);

    mlp_fused<<<NPTS / 64, 256, 0, stream>>>(
        w_m0w1t, m0_b1, w_m0w2t, m0_g, m0_b, f, fbf);

    for (int i = 0; i < 4; ++i) {
        proj_kernel<<<NPTS / 64, 256, 0, stream>>>(
            fbf, w_lfpt + (size_t)i * 9216, y);
        gathermax_kernel<<<NPTS / 16, 256, 0, stream>>>(
            y, knn, lfp_g + i * 96, lfp_b + i * 96, f, fbf);
        if (i & 1) {
            const int jj = i / 2;
            mlp_fused<<<NPTS / 64, 256, 0, stream>>>(
                w_msw1t + (size_t)jj * 36864, ms_b1 + (size_t)jj * 384,
                w_msw2t + (size_t)jj * 36864, ms_g + jj * 96, ms_b + jj * 96, f, fbf);
        }
    }

    head_kernel<<<NPTS / 64, 256, 0, stream>>>(fbf, w_ppt, c_pp, out);
}